// Round 6
// baseline (380.138 us; speedup 1.0000x reference)
//
#include <hip/hip_runtime.h>

#define Bv   2
#define Nv   8192
#define Cv   128
#define KSv  120
#define KNNv 30

// ---------------------------------------------------------------------------
// Compile-time replication of np.random.RandomState(1234).shuffle(arange(8192))
// -> first 120 entries. MT19937 + Fisher-Yates with masked rejection.
// ---------------------------------------------------------------------------
namespace mtns {
struct MTState { unsigned mt[624]; int mti; };
constexpr void mt_seed(MTState& s, unsigned seed) {
  for (int pos = 0; pos < 624; ++pos) {
    s.mt[pos] = seed;
    seed = 1812433253u * (seed ^ (seed >> 30)) + (unsigned)pos + 1u;
  }
  s.mti = 624;
}
constexpr unsigned mt_next(MTState& s) {
  if (s.mti >= 624) {
    for (int i = 0; i < 624; ++i) {
      unsigned y = (s.mt[i] & 0x80000000u) | (s.mt[(i + 1) % 624] & 0x7fffffffu);
      unsigned v = s.mt[(i + 397) % 624] ^ (y >> 1);
      s.mt[i] = (y & 1u) ? (v ^ 0x9908b0dfu) : v;
    }
    s.mti = 0;
  }
  unsigned y = s.mt[s.mti++];
  y ^= y >> 11;
  y ^= (y << 7) & 0x9d2c5680u;
  y ^= (y << 15) & 0xefc60000u;
  y ^= y >> 18;
  return y;
}
struct IdxTable { int v[KSv]; };
constexpr IdxTable make_idx() {
  MTState st{};
  mt_seed(st, 1234u);
  int arr[Nv] = {};
  for (int i = 0; i < Nv; ++i) arr[i] = i;
  for (int i = Nv - 1; i > 0; --i) {
    unsigned mask = (unsigned)i;
    mask |= mask >> 1; mask |= mask >> 2; mask |= mask >> 4;
    mask |= mask >> 8; mask |= mask >> 16;
    unsigned j = 0;
    do { j = mt_next(st) & mask; } while (j > (unsigned)i);
    int tmp = arr[i]; arr[i] = arr[(int)j]; arr[(int)j] = tmp;
  }
  IdxTable out{};
  for (int k = 0; k < KSv; ++k) out.v[k] = arr[k];
  return out;
}
}  // namespace mtns

__constant__ mtns::IdxTable IDX = mtns::make_idx();

__device__ __forceinline__ float wave_sum(float v) {
  #pragma unroll
  for (int m = 32; m; m >>= 1) v += __shfl_xor(v, m);
  return v;
}

// Opaque barrier: keeps x*x and the add as SEPARATE f32 roundings (numpy does
// mult-then-add, no FMA, in pairwise_sum) despite contraction.
__device__ __forceinline__ float opaque(float x) {
  asm volatile("" : "+v"(x));
  return x;
}

// npyv AVX512-mimic f32 dot (EXACT op order from the verified R4 kernel):
// 16 lane-accumulators (c mod 16) FMA in ascending c, then reduce tree.
__device__ __forceinline__ float npyv_dot(const float4* __restrict__ grow, int sw,
                                          const float4* __restrict__ irow) {
  float4 a0 = {0,0,0,0}, a1 = {0,0,0,0}, a2 = {0,0,0,0}, a3 = {0,0,0,0};
  #pragma unroll
  for (int c4 = 0; c4 < 32; c4 += 4) {
    float4 g0 = grow[(c4 + 0) ^ sw]; float4 f0 = irow[c4 + 0];
    float4 g1 = grow[(c4 + 1) ^ sw]; float4 f1 = irow[c4 + 1];
    float4 g2 = grow[(c4 + 2) ^ sw]; float4 f2 = irow[c4 + 2];
    float4 g3 = grow[(c4 + 3) ^ sw]; float4 f3 = irow[c4 + 3];
    a0.x = fmaf(g0.x, f0.x, a0.x); a0.y = fmaf(g0.y, f0.y, a0.y);
    a0.z = fmaf(g0.z, f0.z, a0.z); a0.w = fmaf(g0.w, f0.w, a0.w);
    a1.x = fmaf(g1.x, f1.x, a1.x); a1.y = fmaf(g1.y, f1.y, a1.y);
    a1.z = fmaf(g1.z, f1.z, a1.z); a1.w = fmaf(g1.w, f1.w, a1.w);
    a2.x = fmaf(g2.x, f2.x, a2.x); a2.y = fmaf(g2.y, f2.y, a2.y);
    a2.z = fmaf(g2.z, f2.z, a2.z); a2.w = fmaf(g2.w, f2.w, a2.w);
    a3.x = fmaf(g3.x, f3.x, a3.x); a3.y = fmaf(g3.y, f3.y, a3.y);
    a3.z = fmaf(g3.z, f3.z, a3.z); a3.w = fmaf(g3.w, f3.w, a3.w);
  }
  float4 h0, h1, h;
  h0.x = a0.x + a2.x; h0.y = a0.y + a2.y; h0.z = a0.z + a2.z; h0.w = a0.w + a2.w;
  h1.x = a1.x + a3.x; h1.y = a1.y + a3.y; h1.z = a1.z + a3.z; h1.w = a1.w + a3.w;
  h.x = h0.x + h1.x; h.y = h0.y + h1.y; h.z = h0.z + h1.z; h.w = h0.w + h1.w;
  float sx = h.x + h.z;
  float sy = h.y + h.w;
  return sx + sy;
}

// ---------------------------------------------------------------------------
// k0: per sampled row (b, kp): numpy-pairwise f32 norm; gn32 = row / nrm
// (IEEE f32 div); G[b,kp,o] = feat_s . conv_w[o,:128] + key_pt . conv_w[o,128:]
// ---------------------------------------------------------------------------
__global__ void k0_prepare(const float* __restrict__ points,
                           const float* __restrict__ feature,
                           const float* __restrict__ inst,
                           const float* __restrict__ conv_w,
                           float* __restrict__ gn32W,
                           float* __restrict__ GW) {
  int bk = blockIdx.x;
  int b = bk / KSv, kp = bk % KSv;
  int jg = IDX.v[kp];
  int t = threadIdx.x;
  __shared__ float featS[Cv];
  __shared__ float rowS[Cv];
  __shared__ float ptS[3];
  __shared__ float nAcc[8];
  __shared__ float nrmSh;
  long rowi = (long)b * Nv + jg;
  float iv = inst[rowi * Cv + t];
  rowS[t] = iv;
  featS[t] = feature[rowi * Cv + t];
  if (t < 3) ptS[t] = points[rowi * 3 + t];
  __syncthreads();
  if (t < 8) {
    float x0 = rowS[t];
    float acc = opaque(x0 * x0);
    #pragma unroll
    for (int i = 1; i < 16; ++i) {
      float xv = rowS[8 * i + t];
      acc = acc + opaque(xv * xv);
    }
    nAcc[t] = acc;
  }
  __syncthreads();
  if (t == 0) {
    float res = ((nAcc[0] + nAcc[1]) + (nAcc[2] + nAcc[3])) +
                ((nAcc[4] + nAcc[5]) + (nAcc[6] + nAcc[7]));
    nrmSh = sqrtf(res);
  }
  __syncthreads();
  gn32W[(b * KSv + kp) * Cv + t] = iv / nrmSh;
  const float* cw = conv_w + t * 131;
  float acc = 0.f;
  #pragma unroll 8
  for (int c = 0; c < Cv; ++c) acc = fmaf(featS[c], cw[c], acc);
  acc = fmaf(ptS[0], cw[128], fmaf(ptS[1], cw[129], fmaf(ptS[2], cw[130], acc)));
  GW[(b * KSv + kp) * Cv + t] = acc;
}

// ---------------------------------------------------------------------------
// k2: WAVE-PER-ROW main kernel. 1024 blocks x 512 threads (8 waves); each
// wave owns 2 rows sequentially; zero block barriers in the row loop (all
// cross-lane work via shuffles + wave-private LDS scratch with wave_barrier
// scheduling fences). Selection arithmetic (pairwise norm, f32 div, npyv dot,
// -1.0f shift, stable rank) is bit-identical to the verified R4 kernel.
// Outputs: gamma-selected extremum Msel (8 MB) + per-row group partials.
// ---------------------------------------------------------------------------
__global__ __launch_bounds__(512) void k2_main(
    const float* __restrict__ points,
    const float* __restrict__ inst,
    const float* __restrict__ w1,
    const float* __restrict__ w2,
    const float* __restrict__ conv_w,
    const float* __restrict__ gamma,
    const float* __restrict__ gn32,
    const float* __restrict__ GW,
    float* __restrict__ Msel,
    float2* __restrict__ part) {
  __shared__ float4 gnS[KSv * 32];   // 61440 B, XOR-swizzled rows
  __shared__ float sc[8 * 256];      // 8 KB: per-wave scratch (256 f32 each)

  int bid = blockIdx.x;
  int b = bid >> 9;                  // 512 blocks per batch
  int chunk = bid & 511;             // 16 rows per block
  int tid = threadIdx.x;
  int w = tid >> 6, l = tid & 63;

  const float4* gnG = (const float4*)(gn32 + (long)b * KSv * Cv);
  for (int i = tid; i < KSv * 32; i += 512) {
    int kp = i >> 5, c4 = i & 31;
    gnS[kp * 32 + (c4 ^ (kp & 31))] = gnG[i];
  }
  __syncthreads();                   // the only block barrier

  float* wb = sc + w * 256;          // wave-private scratch
  float2* fnS2 = (float2*)wb;        // [0..127]: raw row, then fn
  float* distS = wb + 128;           // [128..247]: 120 dists
  float* tvp = wb;                   // overlays fn after it's dead
  int*   tip = (int*)(wb + 32);
  float* asp = wb + 64;
  float* atp = wb + 96;

  int c0 = 2 * l, c1 = 2 * l + 1;    // this lane's two channels
  float ga0 = gamma[c0], ga1 = gamma[c1];
  float cwa0 = conv_w[c0 * 131 + 128], cwb0 = conv_w[c0 * 131 + 129],
        cwc0 = conv_w[c0 * 131 + 130];
  float cwa1 = conv_w[c1 * 131 + 128], cwb1 = conv_w[c1 * 131 + 129],
        cwc1 = conv_w[c1 * 131 + 130];
  const float* Gb = GW + (long)b * KSv * Cv;
  const float NINF = -__builtin_inff();

  for (int e = 0; e < 2; ++e) {
    int n = chunk * 16 + 2 * w + e;
    long row = (long)b * Nv + n;
    __builtin_amdgcn_wave_barrier();
    float2 iv2 = *(const float2*)(inst + row * Cv + c0);
    fnS2[l] = iv2;
    float p0 = points[row * 3 + 0];
    float p1 = points[row * 3 + 1];
    float p2 = points[row * 3 + 2];
    __builtin_amdgcn_wave_barrier();
    // numpy pairwise_sum(x*x): 8 sequential accumulators + tree + sqrtf
    float acc = 0.f;
    if (l < 8) {
      float x0 = wb[l];
      acc = opaque(x0 * x0);
      #pragma unroll
      for (int i = 1; i < 16; ++i) {
        float xv = wb[8 * i + l];
        acc = acc + opaque(xv * xv);
      }
    }
    float r0 = __shfl(acc, 0), r1 = __shfl(acc, 1), r2 = __shfl(acc, 2),
          r3 = __shfl(acc, 3), r4 = __shfl(acc, 4), r5 = __shfl(acc, 5),
          r6 = __shfl(acc, 6), r7 = __shfl(acc, 7);
    float nrm = sqrtf(((r0 + r1) + (r2 + r3)) + ((r4 + r5) + (r6 + r7)));
    __builtin_amdgcn_wave_barrier();
    float2 fn2;
    fn2.x = iv2.x / nrm;             // IEEE f32 div (matches np fn bits)
    fn2.y = iv2.y / nrm;
    fnS2[l] = fn2;
    __builtin_amdgcn_wave_barrier();
    // dist: lane l scores t0 = l and t1 = 64+l (l<56)
    const float4* irow = (const float4*)wb;
    float d0 = npyv_dot(gnS + l * 32, l & 31, irow) - 1.0f;
    float d1 = NINF;
    if (l < 56) d1 = npyv_dot(gnS + (64 + l) * 32, l & 31, irow) - 1.0f;
    distS[l] = d0;
    if (l < 56) distS[64 + l] = d1;
    __builtin_amdgcn_wave_barrier();
    // stable rank (index tiebreak) for both t's; d1=-inf lanes rank out
    int rk0 = 0, rk1 = 0;
    const float4* dv = (const float4*)distS;
    int t1 = 64 + l;
    #pragma unroll
    for (int j4 = 0; j4 < KSv / 4; ++j4) {
      float4 w4 = dv[j4];
      int base = j4 * 4;
      rk0 += (w4.x > d0) || (w4.x == d0 && (base + 0) < l);
      rk0 += (w4.y > d0) || (w4.y == d0 && (base + 1) < l);
      rk0 += (w4.z > d0) || (w4.z == d0 && (base + 2) < l);
      rk0 += (w4.w > d0) || (w4.w == d0 && (base + 3) < l);
      rk1 += (w4.x > d1) || (w4.x == d1 && (base + 0) < t1);
      rk1 += (w4.y > d1) || (w4.y == d1 && (base + 1) < t1);
      rk1 += (w4.z > d1) || (w4.z == d1 && (base + 2) < t1);
      rk1 += (w4.w > d1) || (w4.w == d1 && (base + 3) < t1);
    }
    if (rk0 < KNNv) { tvp[rk0] = d0; tip[rk0] = l; }
    if (l < 56 && rk1 < KNNv) { tvp[rk1] = d1; tip[rk1] = t1; }
    __builtin_amdgcn_wave_barrier();
    // a = relu(W1 . topk_dist)
    if (l < KNNv) {
      float a = 0.f;
      #pragma unroll
      for (int k = 0; k < KNNv; ++k) a = fmaf(tvp[k], w1[l * KNNv + k], a);
      asp[l] = fmaxf(a, 0.f);
    }
    __builtin_amdgcn_wave_barrier();
    float a2 = NINF;
    if (l < KNNv) {
      float s2 = 0.f;
      #pragma unroll
      for (int o = 0; o < KNNv; ++o) s2 = fmaf(asp[o], w2[l * KNNv + o], s2);
      a2 = s2;
    }
    // softmax over 30 via wave shuffles (max exact; sum order = smooth path)
    float m = a2;
    #pragma unroll
    for (int msk = 32; msk; msk >>= 1) m = fmaxf(m, __shfl_xor(m, msk));
    float ev = (l < KNNv) ? __expf(a2 - m) : 0.f;
    float ssum = wave_sum(ev);
    float inv = 1.0f / ssum;
    if (l < KNNv) atp[l] = ev * inv;
    __builtin_amdgcn_wave_barrier();
    // y scan: y_k = attn_k * (G[j_k][c] - PW_c); gamma-selected extremum +
    // group sum/sumsq partials
    float pw0 = fmaf(p0, cwa0, fmaf(p1, cwb0, p2 * cwc0));
    float pw1 = fmaf(p0, cwa1, fmaf(p1, cwb1, p2 * cwc1));
    float mx0 = NINF, mn0 = -NINF, mx1 = NINF, mn1 = -NINF;
    float s = 0.f, q = 0.f;
    #pragma unroll
    for (int k = 0; k < KNNv; ++k) {
      float ak = atp[k];
      int jk = tip[k];
      float2 g = *(const float2*)(Gb + jk * Cv + c0);
      float y0 = ak * (g.x - pw0);
      float y1 = ak * (g.y - pw1);
      mx0 = fmaxf(mx0, y0); mn0 = fminf(mn0, y0);
      mx1 = fmaxf(mx1, y1); mn1 = fminf(mn1, y1);
      s += y0 + y1;
      q = fmaf(y0, y0, fmaf(y1, y1, q));
    }
    float2 msel;
    msel.x = (ga0 >= 0.f) ? mx0 : mn0;
    msel.y = (ga1 >= 0.f) ? mx1 : mn1;
    *(float2*)(Msel + row * Cv + c0) = msel;
    // group partials: lanes 0..31 = group 0 (c<64), 32..63 = group 1
    float sg = s, qg = q;
    #pragma unroll
    for (int msk = 16; msk; msk >>= 1) {
      sg += __shfl_xor(sg, msk);
      qg += __shfl_xor(qg, msk);
    }
    if ((l & 31) == 0) part[row * 2 + (l >> 5)] = make_float2(sg, qg);
  }
}

// ---------------------------------------------------------------------------
// k3: reduce per-row group partials -> (mu, rsqrt(var+eps)) per (b, group)
// ---------------------------------------------------------------------------
__global__ void k3_stats(const float2* __restrict__ part,
                         float2* __restrict__ stats) {
  int bg = blockIdx.x;
  int b = bg >> 1, g = bg & 1;
  int tid = threadIdx.x;
  __shared__ double sd[256], qd[256];
  double s = 0, q = 0;
  for (int i = tid; i < Nv; i += 256) {
    float2 p = part[((long)b * Nv + i) * 2 + g];
    s += p.x;
    q += p.y;
  }
  sd[tid] = s; qd[tid] = q;
  __syncthreads();
  for (int st = 128; st > 0; st >>= 1) {
    if (tid < st) { sd[tid] += sd[tid + st]; qd[tid] += qd[tid + st]; }
    __syncthreads();
  }
  if (tid == 0) {
    const double cnt = 64.0 * 30.0 * 8192.0;
    double mu = sd[0] / cnt;
    double var = qd[0] / cnt - mu * mu;
    double rs = 1.0 / sqrt(var + 1e-5);
    stats[bg] = make_float2((float)mu, (float)rs);
  }
}

// ---------------------------------------------------------------------------
// k4: GN affine + leaky on the gamma-selected pooled channel, then 3x256
// output MLP. One block (128 thr) per row.
// ---------------------------------------------------------------------------
__global__ void k4_out(const float* __restrict__ feature,
                       const float* __restrict__ gamma,
                       const float* __restrict__ beta,
                       const float* __restrict__ mlp_w,
                       const float* __restrict__ mlp_b,
                       const float* __restrict__ Msel,
                       const float2* __restrict__ stats,
                       float* __restrict__ out) {
  long row = blockIdx.x;
  int b = (int)(row >> 13), n = (int)(row & (Nv - 1));
  int t = threadIdx.x;
  int g = t >> 6;
  float2 st = stats[b * 2 + g];
  float gam = gamma[t], bet = beta[t];
  float M = Msel[row * Cv + t];
  float yv = fmaf((M - st.x) * st.y, gam, bet);
  yv = (yv >= 0.f) ? yv : 0.2f * yv;
  float fv = feature[row * Cv + t];
  float o0 = yv * mlp_w[0 * 256 + t] + fv * mlp_w[0 * 256 + 128 + t];
  float o1 = yv * mlp_w[1 * 256 + t] + fv * mlp_w[1 * 256 + 128 + t];
  float o2 = yv * mlp_w[2 * 256 + t] + fv * mlp_w[2 * 256 + 128 + t];
  o0 = wave_sum(o0);
  o1 = wave_sum(o1);
  o2 = wave_sum(o2);
  __shared__ float red[2][3];
  if ((t & 63) == 0) { red[t >> 6][0] = o0; red[t >> 6][1] = o1; red[t >> 6][2] = o2; }
  __syncthreads();
  if (t < 3)
    out[(long)b * 3 * Nv + (long)t * Nv + n] = red[0][t] + red[1][t] + mlp_b[t];
}

extern "C" void kernel_launch(void* const* d_in, const int* in_sizes, int n_in,
                              void* d_out, int out_size, void* d_ws, size_t ws_size,
                              hipStream_t stream) {
  const float* points  = (const float*)d_in[0];
  const float* feature = (const float*)d_in[1];
  const float* inst    = (const float*)d_in[2];
  const float* w1      = (const float*)d_in[3];
  const float* w2      = (const float*)d_in[4];
  const float* conv_w  = (const float*)d_in[5];
  const float* gamma   = (const float*)d_in[6];
  const float* beta    = (const float*)d_in[7];
  const float* mlp_w   = (const float*)d_in[8];
  const float* mlp_b   = (const float*)d_in[9];
  float* out = (float*)d_out;

  // workspace layout (bytes):
  //   gn32  [0,       122880)           2*120*128 f32
  //   GW    [122880,  245760)           2*120*128 f32
  //   Msel  [245760,  245760+8MB)       2*8192*128 f32 (gamma-selected)
  //   part  [.., +262144)               2*8192*2 float2
  //   stats [.., +32)                   4 float2
  char* ws = (char*)d_ws;
  float* gn32  = (float*)(ws);
  float* GW    = (float*)(ws + 122880);
  float* Msel  = (float*)(ws + 245760);
  float2* part = (float2*)(ws + 245760 + 8388608);
  float2* stats= (float2*)(ws + 245760 + 8388608 + 262144);

  k0_prepare<<<dim3(Bv * KSv), dim3(128), 0, stream>>>(points, feature, inst,
                                                       conv_w, gn32, GW);
  k2_main<<<dim3(1024), dim3(512), 0, stream>>>(points, inst, w1, w2, conv_w,
                                                gamma, gn32, GW, Msel, part);
  k3_stats<<<dim3(4), dim3(256), 0, stream>>>(part, stats);
  k4_out<<<dim3(Bv * Nv), dim3(128), 0, stream>>>(feature, gamma, beta, mlp_w,
                                                  mlp_b, Msel, stats, out);
}

// Round 7
// 177.007 us; speedup vs baseline: 2.1476x; 2.1476x over previous
//
#include <hip/hip_runtime.h>

#define Bv   2
#define Nv   8192
#define Cv   128
#define KSv  120
#define KNNv 30

// ---------------------------------------------------------------------------
// Compile-time replication of np.random.RandomState(1234).shuffle(arange(8192))
// -> first 120 entries. MT19937 + Fisher-Yates with masked rejection.
// ---------------------------------------------------------------------------
namespace mtns {
struct MTState { unsigned mt[624]; int mti; };
constexpr void mt_seed(MTState& s, unsigned seed) {
  for (int pos = 0; pos < 624; ++pos) {
    s.mt[pos] = seed;
    seed = 1812433253u * (seed ^ (seed >> 30)) + (unsigned)pos + 1u;
  }
  s.mti = 624;
}
constexpr unsigned mt_next(MTState& s) {
  if (s.mti >= 624) {
    for (int i = 0; i < 624; ++i) {
      unsigned y = (s.mt[i] & 0x80000000u) | (s.mt[(i + 1) % 624] & 0x7fffffffu);
      unsigned v = s.mt[(i + 397) % 624] ^ (y >> 1);
      s.mt[i] = (y & 1u) ? (v ^ 0x9908b0dfu) : v;
    }
    s.mti = 0;
  }
  unsigned y = s.mt[s.mti++];
  y ^= y >> 11;
  y ^= (y << 7) & 0x9d2c5680u;
  y ^= (y << 15) & 0xefc60000u;
  y ^= y >> 18;
  return y;
}
struct IdxTable { int v[KSv]; };
constexpr IdxTable make_idx() {
  MTState st{};
  mt_seed(st, 1234u);
  int arr[Nv] = {};
  for (int i = 0; i < Nv; ++i) arr[i] = i;
  for (int i = Nv - 1; i > 0; --i) {
    unsigned mask = (unsigned)i;
    mask |= mask >> 1; mask |= mask >> 2; mask |= mask >> 4;
    mask |= mask >> 8; mask |= mask >> 16;
    unsigned j = 0;
    do { j = mt_next(st) & mask; } while (j > (unsigned)i);
    int tmp = arr[i]; arr[i] = arr[(int)j]; arr[(int)j] = tmp;
  }
  IdxTable out{};
  for (int k = 0; k < KSv; ++k) out.v[k] = arr[k];
  return out;
}
}  // namespace mtns

__constant__ mtns::IdxTable IDX = mtns::make_idx();

__device__ __forceinline__ float wave_sum(float v) {
  #pragma unroll
  for (int m = 32; m; m >>= 1) v += __shfl_xor(v, m);
  return v;
}

// Opaque barrier: keeps x*x and the add as SEPARATE f32 roundings (numpy does
// mult-then-add, no FMA, in pairwise_sum) despite contraction.
__device__ __forceinline__ float opaque(float x) {
  asm volatile("" : "+v"(x));
  return x;
}

// npyv AVX512-mimic f32 dot. Per-accumulator op order is IDENTICAL to the
// verified R4/R6 kernels (chunk j -> acc[j&3], ascending j, same reduce tree);
// only the software blocking (unroll 4, 2 live loads) changed — register
// pressure, not semantics.
__device__ __forceinline__ float npyv_dot(const float4* __restrict__ grow, int sw,
                                          const float4* __restrict__ irow) {
  float4 acc[4];
  acc[0] = float4{0,0,0,0}; acc[1] = float4{0,0,0,0};
  acc[2] = float4{0,0,0,0}; acc[3] = float4{0,0,0,0};
  #pragma unroll 4
  for (int c4 = 0; c4 < 32; ++c4) {
    float4 g = grow[c4 ^ sw];
    float4 f = irow[c4];
    float4& a = acc[c4 & 3];
    a.x = fmaf(g.x, f.x, a.x); a.y = fmaf(g.y, f.y, a.y);
    a.z = fmaf(g.z, f.z, a.z); a.w = fmaf(g.w, f.w, a.w);
  }
  float4 h0, h1, h;
  h0.x = acc[0].x + acc[2].x; h0.y = acc[0].y + acc[2].y;
  h0.z = acc[0].z + acc[2].z; h0.w = acc[0].w + acc[2].w;
  h1.x = acc[1].x + acc[3].x; h1.y = acc[1].y + acc[3].y;
  h1.z = acc[1].z + acc[3].z; h1.w = acc[1].w + acc[3].w;
  h.x = h0.x + h1.x; h.y = h0.y + h1.y; h.z = h0.z + h1.z; h.w = h0.w + h1.w;
  float sx = h.x + h.z;
  float sy = h.y + h.w;
  return sx + sy;
}

// ---------------------------------------------------------------------------
// k0: per sampled row (b, kp): numpy-pairwise f32 norm; gn32 = row / nrm
// (IEEE f32 div); G[b,kp,o] = feat_s . conv_w[o,:128] + key_pt . conv_w[o,128:]
// ---------------------------------------------------------------------------
__global__ void k0_prepare(const float* __restrict__ points,
                           const float* __restrict__ feature,
                           const float* __restrict__ inst,
                           const float* __restrict__ conv_w,
                           float* __restrict__ gn32W,
                           float* __restrict__ GW) {
  int bk = blockIdx.x;
  int b = bk / KSv, kp = bk % KSv;
  int jg = IDX.v[kp];
  int t = threadIdx.x;
  __shared__ float featS[Cv];
  __shared__ float rowS[Cv];
  __shared__ float ptS[3];
  __shared__ float nAcc[8];
  __shared__ float nrmSh;
  long rowi = (long)b * Nv + jg;
  float iv = inst[rowi * Cv + t];
  rowS[t] = iv;
  featS[t] = feature[rowi * Cv + t];
  if (t < 3) ptS[t] = points[rowi * 3 + t];
  __syncthreads();
  if (t < 8) {
    float x0 = rowS[t];
    float acc = opaque(x0 * x0);
    #pragma unroll
    for (int i = 1; i < 16; ++i) {
      float xv = rowS[8 * i + t];
      acc = acc + opaque(xv * xv);
    }
    nAcc[t] = acc;
  }
  __syncthreads();
  if (t == 0) {
    float res = ((nAcc[0] + nAcc[1]) + (nAcc[2] + nAcc[3])) +
                ((nAcc[4] + nAcc[5]) + (nAcc[6] + nAcc[7]));
    nrmSh = sqrtf(res);
  }
  __syncthreads();
  gn32W[(b * KSv + kp) * Cv + t] = iv / nrmSh;
  const float* cw = conv_w + t * 131;
  float acc = 0.f;
  #pragma unroll 8
  for (int c = 0; c < Cv; ++c) acc = fmaf(featS[c], cw[c], acc);
  acc = fmaf(ptS[0], cw[128], fmaf(ptS[1], cw[129], fmaf(ptS[2], cw[130], acc)));
  GW[(b * KSv + kp) * Cv + t] = acc;
}

// ---------------------------------------------------------------------------
// k2: WAVE-PER-ROW main kernel. 1024 blocks x 512 threads (8 waves); each
// wave owns 2 rows sequentially; zero block barriers in the row loop.
// __launch_bounds__(512,1): VGPR cap 256 — R6's bare (512) capped at 128 and
// spilled ~70 VGPRs/row (+500 MB HBM traffic). Row loop unroll disabled and
// rank loop partially unrolled for the same reason.
// Selection arithmetic bit-identical to verified R4/R6.
// ---------------------------------------------------------------------------
__global__ __launch_bounds__(512, 1) void k2_main(
    const float* __restrict__ points,
    const float* __restrict__ inst,
    const float* __restrict__ w1,
    const float* __restrict__ w2,
    const float* __restrict__ conv_w,
    const float* __restrict__ gamma,
    const float* __restrict__ gn32,
    const float* __restrict__ GW,
    float* __restrict__ Msel,
    float2* __restrict__ part) {
  __shared__ float4 gnS[KSv * 32];   // 61440 B, XOR-swizzled rows
  __shared__ float sc[8 * 256];      // 8 KB: per-wave scratch (256 f32 each)

  int bid = blockIdx.x;
  int b = bid >> 9;                  // 512 blocks per batch
  int chunk = bid & 511;             // 16 rows per block
  int tid = threadIdx.x;
  int w = tid >> 6, l = tid & 63;

  const float4* gnG = (const float4*)(gn32 + (long)b * KSv * Cv);
  for (int i = tid; i < KSv * 32; i += 512) {
    int kp = i >> 5, c4 = i & 31;
    gnS[kp * 32 + (c4 ^ (kp & 31))] = gnG[i];
  }
  __syncthreads();                   // the only block barrier

  float* wb = sc + w * 256;          // wave-private scratch
  float2* fnS2 = (float2*)wb;        // [0..127]: raw row, then fn
  float* distS = wb + 128;           // [128..247]: 120 dists
  float* tvp = wb;                   // overlays fn after it's dead
  int*   tip = (int*)(wb + 32);
  float* asp = wb + 64;
  float* atp = wb + 96;

  int c0 = 2 * l, c1 = 2 * l + 1;    // this lane's two channels
  float ga0 = gamma[c0], ga1 = gamma[c1];
  float cwa0 = conv_w[c0 * 131 + 128], cwb0 = conv_w[c0 * 131 + 129],
        cwc0 = conv_w[c0 * 131 + 130];
  float cwa1 = conv_w[c1 * 131 + 128], cwb1 = conv_w[c1 * 131 + 129],
        cwc1 = conv_w[c1 * 131 + 130];
  const float* Gb = GW + (long)b * KSv * Cv;
  const float NINF = -__builtin_inff();

  #pragma clang loop unroll(disable)
  for (int e = 0; e < 2; ++e) {
    int n = chunk * 16 + 2 * w + e;
    long row = (long)b * Nv + n;
    __builtin_amdgcn_wave_barrier();
    float2 iv2 = *(const float2*)(inst + row * Cv + c0);
    fnS2[l] = iv2;
    float p0 = points[row * 3 + 0];
    float p1 = points[row * 3 + 1];
    float p2 = points[row * 3 + 2];
    __builtin_amdgcn_wave_barrier();
    // numpy pairwise_sum(x*x): 8 sequential accumulators + tree + sqrtf
    float acc = 0.f;
    if (l < 8) {
      float x0 = wb[l];
      acc = opaque(x0 * x0);
      #pragma unroll
      for (int i = 1; i < 16; ++i) {
        float xv = wb[8 * i + l];
        acc = acc + opaque(xv * xv);
      }
    }
    float r0 = __shfl(acc, 0), r1 = __shfl(acc, 1), r2 = __shfl(acc, 2),
          r3 = __shfl(acc, 3), r4 = __shfl(acc, 4), r5 = __shfl(acc, 5),
          r6 = __shfl(acc, 6), r7 = __shfl(acc, 7);
    float nrm = sqrtf(((r0 + r1) + (r2 + r3)) + ((r4 + r5) + (r6 + r7)));
    __builtin_amdgcn_wave_barrier();
    float2 fn2;
    fn2.x = iv2.x / nrm;             // IEEE f32 div (matches np fn bits)
    fn2.y = iv2.y / nrm;
    fnS2[l] = fn2;
    __builtin_amdgcn_wave_barrier();
    // dist: lane l scores t0 = l and t1 = 64+l (l<56)
    const float4* irow = (const float4*)wb;
    float d0 = npyv_dot(gnS + l * 32, l & 31, irow) - 1.0f;
    float d1 = NINF;
    if (l < 56) d1 = npyv_dot(gnS + (64 + l) * 32, l & 31, irow) - 1.0f;
    distS[l] = d0;
    if (l < 56) distS[64 + l] = d1;
    __builtin_amdgcn_wave_barrier();
    // stable rank (index tiebreak) for both t's; d1=-inf lanes rank out
    int rk0 = 0, rk1 = 0;
    const float4* dv = (const float4*)distS;
    int t1 = 64 + l;
    #pragma unroll 6
    for (int j4 = 0; j4 < KSv / 4; ++j4) {
      float4 w4 = dv[j4];
      int base = j4 * 4;
      rk0 += (w4.x > d0) || (w4.x == d0 && (base + 0) < l);
      rk0 += (w4.y > d0) || (w4.y == d0 && (base + 1) < l);
      rk0 += (w4.z > d0) || (w4.z == d0 && (base + 2) < l);
      rk0 += (w4.w > d0) || (w4.w == d0 && (base + 3) < l);
      rk1 += (w4.x > d1) || (w4.x == d1 && (base + 0) < t1);
      rk1 += (w4.y > d1) || (w4.y == d1 && (base + 1) < t1);
      rk1 += (w4.z > d1) || (w4.z == d1 && (base + 2) < t1);
      rk1 += (w4.w > d1) || (w4.w == d1 && (base + 3) < t1);
    }
    if (rk0 < KNNv) { tvp[rk0] = d0; tip[rk0] = l; }
    if (l < 56 && rk1 < KNNv) { tvp[rk1] = d1; tip[rk1] = t1; }
    __builtin_amdgcn_wave_barrier();
    // a = relu(W1 . topk_dist)
    if (l < KNNv) {
      float a = 0.f;
      #pragma unroll
      for (int k = 0; k < KNNv; ++k) a = fmaf(tvp[k], w1[l * KNNv + k], a);
      asp[l] = fmaxf(a, 0.f);
    }
    __builtin_amdgcn_wave_barrier();
    float a2 = NINF;
    if (l < KNNv) {
      float s2 = 0.f;
      #pragma unroll
      for (int o = 0; o < KNNv; ++o) s2 = fmaf(asp[o], w2[l * KNNv + o], s2);
      a2 = s2;
    }
    // softmax over 30 via wave shuffles (max exact; sum order = smooth path)
    float m = a2;
    #pragma unroll
    for (int msk = 32; msk; msk >>= 1) m = fmaxf(m, __shfl_xor(m, msk));
    float ev = (l < KNNv) ? __expf(a2 - m) : 0.f;
    float ssum = wave_sum(ev);
    float inv = 1.0f / ssum;
    if (l < KNNv) atp[l] = ev * inv;
    __builtin_amdgcn_wave_barrier();
    // y scan: y_k = attn_k * (G[j_k][c] - PW_c); gamma-selected extremum +
    // group sum/sumsq partials
    float pw0 = fmaf(p0, cwa0, fmaf(p1, cwb0, p2 * cwc0));
    float pw1 = fmaf(p0, cwa1, fmaf(p1, cwb1, p2 * cwc1));
    float mx0 = NINF, mn0 = -NINF, mx1 = NINF, mn1 = -NINF;
    float s = 0.f, q = 0.f;
    #pragma unroll 6
    for (int k = 0; k < KNNv; ++k) {
      float ak = atp[k];
      int jk = tip[k];
      float2 g = *(const float2*)(Gb + jk * Cv + c0);
      float y0 = ak * (g.x - pw0);
      float y1 = ak * (g.y - pw1);
      mx0 = fmaxf(mx0, y0); mn0 = fminf(mn0, y0);
      mx1 = fmaxf(mx1, y1); mn1 = fminf(mn1, y1);
      s += y0 + y1;
      q = fmaf(y0, y0, fmaf(y1, y1, q));
    }
    float2 msel;
    msel.x = (ga0 >= 0.f) ? mx0 : mn0;
    msel.y = (ga1 >= 0.f) ? mx1 : mn1;
    *(float2*)(Msel + row * Cv + c0) = msel;
    // group partials: lanes 0..31 = group 0 (c<64), 32..63 = group 1
    float sg = s, qg = q;
    #pragma unroll
    for (int msk = 16; msk; msk >>= 1) {
      sg += __shfl_xor(sg, msk);
      qg += __shfl_xor(qg, msk);
    }
    if ((l & 31) == 0) part[row * 2 + (l >> 5)] = make_float2(sg, qg);
  }
}

// ---------------------------------------------------------------------------
// k3: reduce per-row group partials -> (mu, rsqrt(var+eps)) per (b, group)
// ---------------------------------------------------------------------------
__global__ void k3_stats(const float2* __restrict__ part,
                         float2* __restrict__ stats) {
  int bg = blockIdx.x;
  int b = bg >> 1, g = bg & 1;
  int tid = threadIdx.x;
  __shared__ double sd[256], qd[256];
  double s = 0, q = 0;
  for (int i = tid; i < Nv; i += 256) {
    float2 p = part[((long)b * Nv + i) * 2 + g];
    s += p.x;
    q += p.y;
  }
  sd[tid] = s; qd[tid] = q;
  __syncthreads();
  for (int st = 128; st > 0; st >>= 1) {
    if (tid < st) { sd[tid] += sd[tid + st]; qd[tid] += qd[tid + st]; }
    __syncthreads();
  }
  if (tid == 0) {
    const double cnt = 64.0 * 30.0 * 8192.0;
    double mu = sd[0] / cnt;
    double var = qd[0] / cnt - mu * mu;
    double rs = 1.0 / sqrt(var + 1e-5);
    stats[bg] = make_float2((float)mu, (float)rs);
  }
}

// ---------------------------------------------------------------------------
// k4: GN affine + leaky on the gamma-selected pooled channel, then 3x256
// output MLP. 2 rows per 256-thread block (same per-row arithmetic as R6).
// ---------------------------------------------------------------------------
__global__ __launch_bounds__(256) void k4_out(
    const float* __restrict__ feature,
    const float* __restrict__ gamma,
    const float* __restrict__ beta,
    const float* __restrict__ mlp_w,
    const float* __restrict__ mlp_b,
    const float* __restrict__ Msel,
    const float2* __restrict__ stats,
    float* __restrict__ out) {
  int rr = threadIdx.x >> 7;
  int t = threadIdx.x & 127;
  long row = (long)blockIdx.x * 2 + rr;
  int b = (int)(row >> 13), n = (int)(row & (Nv - 1));
  int g = t >> 6;
  float2 st = stats[b * 2 + g];
  float gam = gamma[t], bet = beta[t];
  float M = Msel[row * Cv + t];
  float yv = fmaf((M - st.x) * st.y, gam, bet);
  yv = (yv >= 0.f) ? yv : 0.2f * yv;
  float fv = feature[row * Cv + t];
  float o0 = yv * mlp_w[0 * 256 + t] + fv * mlp_w[0 * 256 + 128 + t];
  float o1 = yv * mlp_w[1 * 256 + t] + fv * mlp_w[1 * 256 + 128 + t];
  float o2 = yv * mlp_w[2 * 256 + t] + fv * mlp_w[2 * 256 + 128 + t];
  o0 = wave_sum(o0);
  o1 = wave_sum(o1);
  o2 = wave_sum(o2);
  __shared__ float red[2][2][3];
  if ((t & 63) == 0) {
    red[rr][t >> 6][0] = o0; red[rr][t >> 6][1] = o1; red[rr][t >> 6][2] = o2;
  }
  __syncthreads();
  if (t < 3)
    out[(long)b * 3 * Nv + (long)t * Nv + n] =
        red[rr][0][t] + red[rr][1][t] + mlp_b[t];
}

extern "C" void kernel_launch(void* const* d_in, const int* in_sizes, int n_in,
                              void* d_out, int out_size, void* d_ws, size_t ws_size,
                              hipStream_t stream) {
  const float* points  = (const float*)d_in[0];
  const float* feature = (const float*)d_in[1];
  const float* inst    = (const float*)d_in[2];
  const float* w1      = (const float*)d_in[3];
  const float* w2      = (const float*)d_in[4];
  const float* conv_w  = (const float*)d_in[5];
  const float* gamma   = (const float*)d_in[6];
  const float* beta    = (const float*)d_in[7];
  const float* mlp_w   = (const float*)d_in[8];
  const float* mlp_b   = (const float*)d_in[9];
  float* out = (float*)d_out;

  // workspace layout (bytes):
  //   gn32  [0,       122880)           2*120*128 f32
  //   GW    [122880,  245760)           2*120*128 f32
  //   Msel  [245760,  245760+8MB)       2*8192*128 f32 (gamma-selected)
  //   part  [.., +262144)               2*8192*2 float2
  //   stats [.., +32)                   4 float2
  char* ws = (char*)d_ws;
  float* gn32  = (float*)(ws);
  float* GW    = (float*)(ws + 122880);
  float* Msel  = (float*)(ws + 245760);
  float2* part = (float2*)(ws + 245760 + 8388608);
  float2* stats= (float2*)(ws + 245760 + 8388608 + 262144);

  k0_prepare<<<dim3(Bv * KSv), dim3(128), 0, stream>>>(points, feature, inst,
                                                       conv_w, gn32, GW);
  k2_main<<<dim3(1024), dim3(512), 0, stream>>>(points, inst, w1, w2, conv_w,
                                                gamma, gn32, GW, Msel, part);
  k3_stats<<<dim3(4), dim3(256), 0, stream>>>(part, stats);
  k4_out<<<dim3(Bv * Nv / 2), dim3(256), 0, stream>>>(feature, gamma, beta,
                                                      mlp_w, mlp_b, Msel,
                                                      stats, out);
}

// Round 8
// 172.895 us; speedup vs baseline: 2.1987x; 1.0238x over previous
//
#include <hip/hip_runtime.h>

#define Bv   2
#define Nv   8192
#define Cv   128
#define KSv  120
#define KNNv 30

// ---------------------------------------------------------------------------
// Compile-time replication of np.random.RandomState(1234).shuffle(arange(8192))
// -> first 120 entries. MT19937 + Fisher-Yates with masked rejection.
// ---------------------------------------------------------------------------
namespace mtns {
struct MTState { unsigned mt[624]; int mti; };
constexpr void mt_seed(MTState& s, unsigned seed) {
  for (int pos = 0; pos < 624; ++pos) {
    s.mt[pos] = seed;
    seed = 1812433253u * (seed ^ (seed >> 30)) + (unsigned)pos + 1u;
  }
  s.mti = 624;
}
constexpr unsigned mt_next(MTState& s) {
  if (s.mti >= 624) {
    for (int i = 0; i < 624; ++i) {
      unsigned y = (s.mt[i] & 0x80000000u) | (s.mt[(i + 1) % 624] & 0x7fffffffu);
      unsigned v = s.mt[(i + 397) % 624] ^ (y >> 1);
      s.mt[i] = (y & 1u) ? (v ^ 0x9908b0dfu) : v;
    }
    s.mti = 0;
  }
  unsigned y = s.mt[s.mti++];
  y ^= y >> 11;
  y ^= (y << 7) & 0x9d2c5680u;
  y ^= (y << 15) & 0xefc60000u;
  y ^= y >> 18;
  return y;
}
struct IdxTable { int v[KSv]; };
constexpr IdxTable make_idx() {
  MTState st{};
  mt_seed(st, 1234u);
  int arr[Nv] = {};
  for (int i = 0; i < Nv; ++i) arr[i] = i;
  for (int i = Nv - 1; i > 0; --i) {
    unsigned mask = (unsigned)i;
    mask |= mask >> 1; mask |= mask >> 2; mask |= mask >> 4;
    mask |= mask >> 8; mask |= mask >> 16;
    unsigned j = 0;
    do { j = mt_next(st) & mask; } while (j > (unsigned)i);
    int tmp = arr[i]; arr[i] = arr[(int)j]; arr[(int)j] = tmp;
  }
  IdxTable out{};
  for (int k = 0; k < KSv; ++k) out.v[k] = arr[k];
  return out;
}
}  // namespace mtns

__constant__ mtns::IdxTable IDX = mtns::make_idx();

__device__ __forceinline__ float wave_sum(float v) {
  #pragma unroll
  for (int m = 32; m; m >>= 1) v += __shfl_xor(v, m);
  return v;
}

// Opaque barrier: keeps x*x and the add as SEPARATE f32 roundings (numpy does
// mult-then-add, no FMA, in pairwise_sum) despite contraction.
__device__ __forceinline__ float opaque(float x) {
  asm volatile("" : "+v"(x));
  return x;
}

// Wave-uniform broadcasts on the VALU/scalar path (ignores exec mask) —
// replaces LDS broadcast reads to offload the DS pipe.
__device__ __forceinline__ float rdf(float v, int k) {
  return __int_as_float(__builtin_amdgcn_readlane(__float_as_int(v), k));
}
__device__ __forceinline__ int rdi(int v, int k) {
  return __builtin_amdgcn_readlane(v, k);
}

// npyv reduce tree (identical op order to verified R4/R7 kernels)
__device__ __forceinline__ float npyv_reduce(const float4* a) {
  float4 h0, h1, h;
  h0.x = a[0].x + a[2].x; h0.y = a[0].y + a[2].y;
  h0.z = a[0].z + a[2].z; h0.w = a[0].w + a[2].w;
  h1.x = a[1].x + a[3].x; h1.y = a[1].y + a[3].y;
  h1.z = a[1].z + a[3].z; h1.w = a[1].w + a[3].w;
  h.x = h0.x + h1.x; h.y = h0.y + h1.y; h.z = h0.z + h1.z; h.w = h0.w + h1.w;
  float sx = h.x + h.z;
  float sy = h.y + h.w;
  return sx + sy;
}

// ---------------------------------------------------------------------------
// k0: per sampled row (b, kp): numpy-pairwise f32 norm; gn32 = row / nrm
// (IEEE f32 div); G[b,kp,o] = feat_s . conv_w[o,:128] + key_pt . conv_w[o,128:]
// Also zeroes the k2 ticket counter.
// ---------------------------------------------------------------------------
__global__ void k0_prepare(const float* __restrict__ points,
                           const float* __restrict__ feature,
                           const float* __restrict__ inst,
                           const float* __restrict__ conv_w,
                           float* __restrict__ gn32W,
                           float* __restrict__ GW,
                           int* __restrict__ counter) {
  int bk = blockIdx.x;
  int b = bk / KSv, kp = bk % KSv;
  int jg = IDX.v[kp];
  int t = threadIdx.x;
  if (bk == 0 && t == 0) *counter = 0;
  __shared__ float featS[Cv];
  __shared__ float rowS[Cv];
  __shared__ float ptS[3];
  __shared__ float nAcc[8];
  __shared__ float nrmSh;
  long rowi = (long)b * Nv + jg;
  float iv = inst[rowi * Cv + t];
  rowS[t] = iv;
  featS[t] = feature[rowi * Cv + t];
  if (t < 3) ptS[t] = points[rowi * 3 + t];
  __syncthreads();
  if (t < 8) {
    float x0 = rowS[t];
    float acc = opaque(x0 * x0);
    #pragma unroll
    for (int i = 1; i < 16; ++i) {
      float xv = rowS[8 * i + t];
      acc = acc + opaque(xv * xv);
    }
    nAcc[t] = acc;
  }
  __syncthreads();
  if (t == 0) {
    float res = ((nAcc[0] + nAcc[1]) + (nAcc[2] + nAcc[3])) +
                ((nAcc[4] + nAcc[5]) + (nAcc[6] + nAcc[7]));
    nrmSh = sqrtf(res);
  }
  __syncthreads();
  gn32W[(b * KSv + kp) * Cv + t] = iv / nrmSh;
  const float* cw = conv_w + t * 131;
  float acc = 0.f;
  #pragma unroll 8
  for (int c = 0; c < Cv; ++c) acc = fmaf(featS[c], cw[c], acc);
  acc = fmaf(ptS[0], cw[128], fmaf(ptS[1], cw[129], fmaf(ptS[2], cw[130], acc)));
  GW[(b * KSv + kp) * Cv + t] = acc;
}

// ---------------------------------------------------------------------------
// k2: wave-per-ROW-PAIR main kernel. 1024 blocks x 512 threads (8 waves);
// each wave processes 2 rows SIMULTANEOUSLY through the dot phase so every
// gnS chunk read feeds both rows (dot DS reads halved: 128->64 b128/row).
// All small broadcast loops (W1/W2 matvec, y-scan attn/index) use readlane
// (VALU) on lane-resident values instead of LDS reads. GN stats partials are
// block-reduced and the LAST block (threadfence+atomic ticket) computes
// stats in fixed-order f64 (deterministic) — k3 eliminated.
// Selection arithmetic bit-identical to verified R4/R7.
// ---------------------------------------------------------------------------
__global__ __launch_bounds__(512, 4) void k2_main(
    const float* __restrict__ points,
    const float* __restrict__ inst,
    const float* __restrict__ w1,
    const float* __restrict__ w2,
    const float* __restrict__ conv_w,
    const float* __restrict__ gamma,
    const float* __restrict__ gn32,
    const float* __restrict__ GW,
    float* __restrict__ Msel,
    float2* __restrict__ part,
    int* __restrict__ counter,
    float2* __restrict__ stats) {
  __shared__ float4 gnS[KSv * 32];   // 61440 B, XOR-swizzled rows
  __shared__ float sc[8 * 512];      // 16384 B: per-wave scratch
  __shared__ float2 partS[16];       // per-(wave,group) block partials
  __shared__ int lastFlag;

  int bid = blockIdx.x;
  int b = bid >> 9;                  // 512 blocks per batch
  int chunk = bid & 511;             // 16 rows per block
  int tid = threadIdx.x;
  int w = tid >> 6, l = tid & 63;

  const float4* gnG = (const float4*)(gn32 + (long)b * KSv * Cv);
  for (int i = tid; i < KSv * 32; i += 512) {
    int kp = i >> 5, c4 = i & 31;
    gnS[kp * 32 + (c4 ^ (kp & 31))] = gnG[i];
  }
  __syncthreads();

  float* wb = sc + w * 512;          // wave-private scratch
  float* fnA = wb;                   // 128: row A (raw, then fn)
  float* fnB = wb + 128;             // 128: row B
  float* dsA = wb + 256;             // 128: dists A; tv/ti overlay after rank
  float* dsB = wb + 384;             // 128: dists B
  float* tvA = dsA; int* tiA = (int*)(dsA + 32);
  float* tvB = dsB; int* tiB = (int*)(dsB + 32);

  int c0 = 2 * l;
  int nA = chunk * 16 + 2 * w;
  long rowA = (long)b * Nv + nA;
  long rowB = rowA + 1;
  const float* Gb = GW + (long)b * KSv * Cv;
  const float NINF = -__builtin_inff();

  // ---- stage raw inst rows ----
  float2 ivA = *(const float2*)(inst + rowA * Cv + c0);
  float2 ivB = *(const float2*)(inst + rowB * Cv + c0);
  ((float2*)fnA)[l] = ivA;
  ((float2*)fnB)[l] = ivB;
  __builtin_amdgcn_wave_barrier();

  // ---- numpy pairwise norms: lanes 0-7 -> A accs, 8-15 -> B accs ----
  float acc = 0.f;
  if (l < 16) {
    const float* xr = (l < 8) ? fnA : fnB;
    int j = l & 7;
    float x0 = xr[j];
    acc = opaque(x0 * x0);
    #pragma unroll
    for (int i = 1; i < 16; ++i) {
      float xv = xr[8 * i + j];
      acc = acc + opaque(xv * xv);
    }
  }
  float nrmA = sqrtf(((rdf(acc, 0) + rdf(acc, 1)) + (rdf(acc, 2) + rdf(acc, 3))) +
                     ((rdf(acc, 4) + rdf(acc, 5)) + (rdf(acc, 6) + rdf(acc, 7))));
  float nrmB = sqrtf(((rdf(acc, 8) + rdf(acc, 9)) + (rdf(acc, 10) + rdf(acc, 11))) +
                     ((rdf(acc, 12) + rdf(acc, 13)) + (rdf(acc, 14) + rdf(acc, 15))));
  __builtin_amdgcn_wave_barrier();
  float2 fA2, fB2;
  fA2.x = ivA.x / nrmA; fA2.y = ivA.y / nrmA;   // IEEE f32 div = np fn bits
  fB2.x = ivB.x / nrmB; fB2.y = ivB.y / nrmB;
  ((float2*)fnA)[l] = fA2;
  ((float2*)fnB)[l] = fB2;
  __builtin_amdgcn_wave_barrier();

  // ---- paired npyv dots: lane l scores key rows t0=l, t1=64+l (l<56) ----
  const float4* fA4 = (const float4*)fnA;
  const float4* fB4 = (const float4*)fnB;
  int sw = l & 31;
  const float4* g0r = gnS + l * 32;
  int r1 = 64 + l; if (r1 > KSv - 1) r1 = KSv - 1;   // clamp; d1 unused l>=56
  const float4* g1r = gnS + r1 * 32;
  float4 aA0[4], aA1[4], aB0[4], aB1[4];
  #pragma unroll
  for (int i = 0; i < 4; ++i) {
    aA0[i] = float4{0,0,0,0}; aA1[i] = float4{0,0,0,0};
    aB0[i] = float4{0,0,0,0}; aB1[i] = float4{0,0,0,0};
  }
  #pragma unroll 4
  for (int c4 = 0; c4 < 32; ++c4) {
    float4 fa = fA4[c4];
    float4 fb = fB4[c4];
    float4 g0 = g0r[c4 ^ sw];
    float4 g1 = g1r[c4 ^ sw];
    int m = c4 & 3;
    aA0[m].x = fmaf(g0.x, fa.x, aA0[m].x); aA0[m].y = fmaf(g0.y, fa.y, aA0[m].y);
    aA0[m].z = fmaf(g0.z, fa.z, aA0[m].z); aA0[m].w = fmaf(g0.w, fa.w, aA0[m].w);
    aB0[m].x = fmaf(g0.x, fb.x, aB0[m].x); aB0[m].y = fmaf(g0.y, fb.y, aB0[m].y);
    aB0[m].z = fmaf(g0.z, fb.z, aB0[m].z); aB0[m].w = fmaf(g0.w, fb.w, aB0[m].w);
    aA1[m].x = fmaf(g1.x, fa.x, aA1[m].x); aA1[m].y = fmaf(g1.y, fa.y, aA1[m].y);
    aA1[m].z = fmaf(g1.z, fa.z, aA1[m].z); aA1[m].w = fmaf(g1.w, fa.w, aA1[m].w);
    aB1[m].x = fmaf(g1.x, fb.x, aB1[m].x); aB1[m].y = fmaf(g1.y, fb.y, aB1[m].y);
    aB1[m].z = fmaf(g1.z, fb.z, aB1[m].z); aB1[m].w = fmaf(g1.w, fb.w, aB1[m].w);
  }
  float d0A = npyv_reduce(aA0) - 1.0f;
  float d1A = npyv_reduce(aA1) - 1.0f;
  float d0B = npyv_reduce(aB0) - 1.0f;
  float d1B = npyv_reduce(aB1) - 1.0f;

  dsA[l] = d0A;
  dsB[l] = d0B;
  if (l < 56) { dsA[64 + l] = d1A; dsB[64 + l] = d1B; }
  __builtin_amdgcn_wave_barrier();

  // ---- stable ranks (index tiebreak); invalid t1 lanes rank out via NINF --
  float d1Ar = (l < 56) ? d1A : NINF;
  float d1Br = (l < 56) ? d1B : NINF;
  int rk0A = 0, rk1A = 0, rk0B = 0, rk1B = 0;
  const float4* dvA = (const float4*)dsA;
  const float4* dvB = (const float4*)dsB;
  int t1 = 64 + l;
  #pragma unroll 5
  for (int j4 = 0; j4 < KSv / 4; ++j4) {
    float4 wA = dvA[j4];
    float4 wB = dvB[j4];
    int base = j4 * 4;
    rk0A += (wA.x > d0A) || (wA.x == d0A && (base + 0) < l);
    rk0A += (wA.y > d0A) || (wA.y == d0A && (base + 1) < l);
    rk0A += (wA.z > d0A) || (wA.z == d0A && (base + 2) < l);
    rk0A += (wA.w > d0A) || (wA.w == d0A && (base + 3) < l);
    rk1A += (wA.x > d1Ar) || (wA.x == d1Ar && (base + 0) < t1);
    rk1A += (wA.y > d1Ar) || (wA.y == d1Ar && (base + 1) < t1);
    rk1A += (wA.z > d1Ar) || (wA.z == d1Ar && (base + 2) < t1);
    rk1A += (wA.w > d1Ar) || (wA.w == d1Ar && (base + 3) < t1);
    rk0B += (wB.x > d0B) || (wB.x == d0B && (base + 0) < l);
    rk0B += (wB.y > d0B) || (wB.y == d0B && (base + 1) < l);
    rk0B += (wB.z > d0B) || (wB.z == d0B && (base + 2) < l);
    rk0B += (wB.w > d0B) || (wB.w == d0B && (base + 3) < l);
    rk1B += (wB.x > d1Br) || (wB.x == d1Br && (base + 0) < t1);
    rk1B += (wB.y > d1Br) || (wB.y == d1Br && (base + 1) < t1);
    rk1B += (wB.z > d1Br) || (wB.z == d1Br && (base + 2) < t1);
    rk1B += (wB.w > d1Br) || (wB.w == d1Br && (base + 3) < t1);
  }
  __builtin_amdgcn_wave_barrier();     // rank reads done; overlay dist slabs
  if (rk0A < KNNv) { tvA[rk0A] = d0A; tiA[rk0A] = l; }
  if (l < 56 && rk1A < KNNv) { tvA[rk1A] = d1A; tiA[rk1A] = t1; }
  if (rk0B < KNNv) { tvB[rk0B] = d0B; tiB[rk0B] = l; }
  if (l < 56 && rk1B < KNNv) { tvB[rk1B] = d1B; tiB[rk1B] = t1; }
  __builtin_amdgcn_wave_barrier();
  // self-load: lane k holds topk slot k in registers
  float mytvA = 0.f, mytvB = 0.f;
  int mytiA = 0, mytiB = 0;
  if (l < KNNv) {
    mytvA = tvA[l]; mytiA = tiA[l];
    mytvB = tvB[l]; mytiB = tiB[l];
  }

  // ---- a = relu(W1 . topk) ; a2 = W2 . a  (readlane broadcasts) ----
  float aA = 0.f, aB = 0.f;
  if (l < KNNv) {
    const float* w1r = w1 + l * KNNv;
    #pragma unroll 6
    for (int k = 0; k < KNNv; ++k) {
      float w1k = w1r[k];
      aA = fmaf(rdf(mytvA, k), w1k, aA);
      aB = fmaf(rdf(mytvB, k), w1k, aB);
    }
    aA = fmaxf(aA, 0.f);
    aB = fmaxf(aB, 0.f);
  }
  float a2A = NINF, a2B = NINF;
  if (l < KNNv) {
    const float* w2r = w2 + l * KNNv;
    float sA2 = 0.f, sB2 = 0.f;
    #pragma unroll 6
    for (int o = 0; o < KNNv; ++o) {
      float w2o = w2r[o];
      sA2 = fmaf(rdf(aA, o), w2o, sA2);
      sB2 = fmaf(rdf(aB, o), w2o, sB2);
    }
    a2A = sA2; a2B = sB2;
  }

  // ---- softmax over 30 (shuffle trees; same op order as R7) ----
  float mA = a2A, mB = a2B;
  #pragma unroll
  for (int msk = 32; msk; msk >>= 1) {
    mA = fmaxf(mA, __shfl_xor(mA, msk));
    mB = fmaxf(mB, __shfl_xor(mB, msk));
  }
  float evA = (l < KNNv) ? __expf(a2A - mA) : 0.f;
  float evB = (l < KNNv) ? __expf(a2B - mB) : 0.f;
  float invA = 1.0f / wave_sum(evA);
  float invB = 1.0f / wave_sum(evB);
  float atpA = evA * invA;
  float atpB = evB * invB;

  // ---- y scan: y_k = attn_k * (G[j_k][c] - PW_c) ----
  float pA0 = points[rowA * 3 + 0], pA1 = points[rowA * 3 + 1],
        pA2 = points[rowA * 3 + 2];
  float pB0 = points[rowB * 3 + 0], pB1 = points[rowB * 3 + 1],
        pB2 = points[rowB * 3 + 2];
  int c1 = c0 + 1;
  float cwa0 = conv_w[c0 * 131 + 128], cwb0 = conv_w[c0 * 131 + 129],
        cwc0 = conv_w[c0 * 131 + 130];
  float cwa1 = conv_w[c1 * 131 + 128], cwb1 = conv_w[c1 * 131 + 129],
        cwc1 = conv_w[c1 * 131 + 130];
  float pwA0 = fmaf(pA0, cwa0, fmaf(pA1, cwb0, pA2 * cwc0));
  float pwA1 = fmaf(pA0, cwa1, fmaf(pA1, cwb1, pA2 * cwc1));
  float pwB0 = fmaf(pB0, cwa0, fmaf(pB1, cwb0, pB2 * cwc0));
  float pwB1 = fmaf(pB0, cwa1, fmaf(pB1, cwb1, pB2 * cwc1));
  float mxA0 = NINF, mnA0 = -NINF, mxA1 = NINF, mnA1 = -NINF;
  float mxB0 = NINF, mnB0 = -NINF, mxB1 = NINF, mnB1 = -NINF;
  float sA = 0.f, qA = 0.f, sB = 0.f, qB = 0.f;
  #pragma unroll 5
  for (int k = 0; k < KNNv; ++k) {
    float akA = rdf(atpA, k);
    float akB = rdf(atpB, k);
    int jkA = rdi(mytiA, k);
    int jkB = rdi(mytiB, k);
    float2 gA = *(const float2*)(Gb + jkA * Cv + c0);
    float2 gB = *(const float2*)(Gb + jkB * Cv + c0);
    float yA0 = akA * (gA.x - pwA0);
    float yA1 = akA * (gA.y - pwA1);
    float yB0 = akB * (gB.x - pwB0);
    float yB1 = akB * (gB.y - pwB1);
    mxA0 = fmaxf(mxA0, yA0); mnA0 = fminf(mnA0, yA0);
    mxA1 = fmaxf(mxA1, yA1); mnA1 = fminf(mnA1, yA1);
    mxB0 = fmaxf(mxB0, yB0); mnB0 = fminf(mnB0, yB0);
    mxB1 = fmaxf(mxB1, yB1); mnB1 = fminf(mnB1, yB1);
    sA += yA0 + yA1;
    qA = fmaf(yA0, yA0, fmaf(yA1, yA1, qA));
    sB += yB0 + yB1;
    qB = fmaf(yB0, yB0, fmaf(yB1, yB1, qB));
  }
  float ga0 = gamma[c0], ga1 = gamma[c1];
  float2 mselA, mselB;
  mselA.x = (ga0 >= 0.f) ? mxA0 : mnA0;
  mselA.y = (ga1 >= 0.f) ? mxA1 : mnA1;
  mselB.x = (ga0 >= 0.f) ? mxB0 : mnB0;
  mselB.y = (ga1 >= 0.f) ? mxB1 : mnB1;
  *(float2*)(Msel + rowA * Cv + c0) = mselA;
  *(float2*)(Msel + rowB * Cv + c0) = mselB;

  // ---- GN partials: lanes 0-31 = group 0 (ch<64), 32-63 = group 1 ----
  float sg = sA + sB, qg = qA + qB;
  #pragma unroll
  for (int msk = 16; msk; msk >>= 1) {
    sg += __shfl_xor(sg, msk);
    qg += __shfl_xor(qg, msk);
  }
  if ((l & 31) == 0) partS[w * 2 + (l >> 5)] = make_float2(sg, qg);
  __syncthreads();
  if (tid == 0) {
    float s0 = 0.f, q0 = 0.f, s1 = 0.f, q1 = 0.f;
    #pragma unroll
    for (int wv = 0; wv < 8; ++wv) {
      s0 += partS[wv * 2].x;     q0 += partS[wv * 2].y;
      s1 += partS[wv * 2 + 1].x; q1 += partS[wv * 2 + 1].y;
    }
    part[bid * 2 + 0] = make_float2(s0, q0);
    part[bid * 2 + 1] = make_float2(s1, q1);
    __threadfence();
    int old = atomicAdd(counter, 1);
    lastFlag = (old == (int)gridDim.x - 1);
  }
  __syncthreads();
  if (lastFlag && w < 4) {
    // wave w handles (bb = w>>1, g = w&1); fixed-order f64 -> deterministic
    int bb = w >> 1, g = w & 1;
    double s = 0.0, q = 0.0;
    #pragma unroll
    for (int i = 0; i < 8; ++i) {
      float2 p = part[(bb * 512 + l + 64 * i) * 2 + g];
      s += (double)p.x;
      q += (double)p.y;
    }
    #pragma unroll
    for (int msk = 32; msk; msk >>= 1) {
      s += __shfl_xor(s, msk);
      q += __shfl_xor(q, msk);
    }
    if (l == 0) {
      const double cnt = 64.0 * 30.0 * 8192.0;
      double mu = s / cnt;
      double var = q / cnt - mu * mu;
      stats[bb * 2 + g] = make_float2((float)mu, (float)(1.0 / sqrt(var + 1e-5)));
    }
  }
}

// ---------------------------------------------------------------------------
// k4: GN affine + leaky on the gamma-selected pooled channel, then 3x256
// output MLP. 2 rows per 256-thread block.
// ---------------------------------------------------------------------------
__global__ __launch_bounds__(256) void k4_out(
    const float* __restrict__ feature,
    const float* __restrict__ gamma,
    const float* __restrict__ beta,
    const float* __restrict__ mlp_w,
    const float* __restrict__ mlp_b,
    const float* __restrict__ Msel,
    const float2* __restrict__ stats,
    float* __restrict__ out) {
  int rr = threadIdx.x >> 7;
  int t = threadIdx.x & 127;
  long row = (long)blockIdx.x * 2 + rr;
  int b = (int)(row >> 13), n = (int)(row & (Nv - 1));
  int g = t >> 6;
  float2 st = stats[b * 2 + g];
  float gam = gamma[t], bet = beta[t];
  float M = Msel[row * Cv + t];
  float yv = fmaf((M - st.x) * st.y, gam, bet);
  yv = (yv >= 0.f) ? yv : 0.2f * yv;
  float fv = feature[row * Cv + t];
  float o0 = yv * mlp_w[0 * 256 + t] + fv * mlp_w[0 * 256 + 128 + t];
  float o1 = yv * mlp_w[1 * 256 + t] + fv * mlp_w[1 * 256 + 128 + t];
  float o2 = yv * mlp_w[2 * 256 + t] + fv * mlp_w[2 * 256 + 128 + t];
  o0 = wave_sum(o0);
  o1 = wave_sum(o1);
  o2 = wave_sum(o2);
  __shared__ float red[2][2][3];
  if ((t & 63) == 0) {
    red[rr][t >> 6][0] = o0; red[rr][t >> 6][1] = o1; red[rr][t >> 6][2] = o2;
  }
  __syncthreads();
  if (t < 3)
    out[(long)b * 3 * Nv + (long)t * Nv + n] =
        red[rr][0][t] + red[rr][1][t] + mlp_b[t];
}

extern "C" void kernel_launch(void* const* d_in, const int* in_sizes, int n_in,
                              void* d_out, int out_size, void* d_ws, size_t ws_size,
                              hipStream_t stream) {
  const float* points  = (const float*)d_in[0];
  const float* feature = (const float*)d_in[1];
  const float* inst    = (const float*)d_in[2];
  const float* w1      = (const float*)d_in[3];
  const float* w2      = (const float*)d_in[4];
  const float* conv_w  = (const float*)d_in[5];
  const float* gamma   = (const float*)d_in[6];
  const float* beta    = (const float*)d_in[7];
  const float* mlp_w   = (const float*)d_in[8];
  const float* mlp_b   = (const float*)d_in[9];
  float* out = (float*)d_out;

  // workspace layout (bytes):
  //   gn32    [0,       122880)        2*120*128 f32
  //   GW      [122880,  245760)        2*120*128 f32
  //   Msel    [245760,  +8MB)          2*8192*128 f32 (gamma-selected)
  //   part    [8634368, +16384)        1024*2 float2 (block partials)
  //   counter [8650752, +64)           int ticket
  //   stats   [8650816, +32)           4 float2
  char* ws = (char*)d_ws;
  float* gn32   = (float*)(ws);
  float* GW     = (float*)(ws + 122880);
  float* Msel   = (float*)(ws + 245760);
  float2* part  = (float2*)(ws + 8634368);
  int* counter  = (int*)(ws + 8650752);
  float2* stats = (float2*)(ws + 8650816);

  k0_prepare<<<dim3(Bv * KSv), dim3(128), 0, stream>>>(points, feature, inst,
                                                       conv_w, gn32, GW, counter);
  k2_main<<<dim3(1024), dim3(512), 0, stream>>>(points, inst, w1, w2, conv_w,
                                                gamma, gn32, GW, Msel, part,
                                                counter, stats);
  k4_out<<<dim3(Bv * Nv / 2), dim3(256), 0, stream>>>(feature, gamma, beta,
                                                      mlp_w, mlp_b, Msel,
                                                      stats, out);
}